// Round 1
// baseline (1063.705 us; speedup 1.0000x reference)
//
#include <hip/hip_runtime.h>
#include <stdint.h>

// Problem constants
#define BB 2
#define SS 2048
#define HIDD 2048
#define HH 16
#define KVH 4
#define DD 128
#define KDIM 2048

typedef short bf16x4 __attribute__((ext_vector_type(4)));
typedef short bf16x8 __attribute__((ext_vector_type(8)));
typedef float f32x4 __attribute__((ext_vector_type(4)));

__device__ __forceinline__ unsigned short f2b(float f) {
  union { float f; unsigned u; } v; v.f = f;
  unsigned r = v.u + 0x7FFFu + ((v.u >> 16) & 1u);
  return (unsigned short)(r >> 16);
}

// Load an 8-element bf16 MFMA fragment: elems 0-3 at p[0..3], elems 4-7 at p[16..19]
// (matches 16x16x32 layout: k = (lane>>4)*4 + (e&3) + 16*(e>>2))
__device__ __forceinline__ bf16x8 ld_frag(const unsigned short* p) {
  union { bf16x8 v8; bf16x4 v4[2]; } u;
  u.v4[0] = *reinterpret_cast<const bf16x4*>(p);
  u.v4[1] = *reinterpret_cast<const bf16x4*>(p + 16);
  return u.v8;
}

__global__ __launch_bounds__(256) void k_convert(const float* __restrict__ in,
                                                 unsigned short* __restrict__ out, int n4) {
  int i = blockIdx.x * 256 + threadIdx.x;
  int stride = gridDim.x * 256;
  for (; i < n4; i += stride) {
    float4 v = reinterpret_cast<const float4*>(in)[i];
    ushort4 o;
    o.x = f2b(v.x); o.y = f2b(v.y); o.z = f2b(v.z); o.w = f2b(v.w);
    reinterpret_cast<ushort4*>(out)[i] = o;
  }
}

// in: (K,N) fp32 row-major -> out: (N,K) bf16 row-major
__global__ __launch_bounds__(256) void k_transpose(const float* __restrict__ in,
                                                   unsigned short* __restrict__ out,
                                                   int K, int N) {
  __shared__ float tile[32][33];
  int n0 = blockIdx.x * 32, k0 = blockIdx.y * 32;
  int tx = threadIdx.x, ty = threadIdx.y;
#pragma unroll
  for (int j = 0; j < 32; j += 8)
    tile[ty + j][tx] = in[(size_t)(k0 + ty + j) * N + n0 + tx];
  __syncthreads();
#pragma unroll
  for (int j = 0; j < 32; j += 8)
    out[(size_t)(n0 + ty + j) * K + k0 + tx] = f2b(tile[tx][ty + j]);
}

// C = A(M x K) * Bt(N x K)^T, bf16 inputs, 128x128 tile, 4 waves, 4x4 frags each.
// EPI 0: plain fp32 store to outF (ldc=2048).
// EPI 1: QKV epilogue with fused RoPE + scatter.
template <int EPI>
__global__ __launch_bounds__(256) void k_gemm(
    const unsigned short* __restrict__ A, const unsigned short* __restrict__ Bt,
    float* __restrict__ outF, unsigned short* __restrict__ qws,
    unsigned short* __restrict__ kws, unsigned short* __restrict__ vTws,
    float* __restrict__ koutF, float* __restrict__ voutF,
    const float* __restrict__ cosT, const float* __restrict__ sinT) {
  constexpr int SKP = 40;  // padded LDS row stride (bf16 elems): 80B rows, bank-balanced
  __shared__ __align__(16) unsigned short lA[128 * SKP];
  __shared__ __align__(16) unsigned short lB[128 * SKP];
  const int rowbase = blockIdx.x * 128;
  const int colbase = blockIdx.y * 128;
  const int t = threadIdx.x;
  const int wid = t >> 6, lane = t & 63;
  const int g = lane >> 4, c = lane & 15;
  const int wrow = (wid >> 1) * 64, wcol = (wid & 1) * 64;

  // staging: thread t covers 16 elems (32B) of row t>>1 at k-offset (t&1)*16
  const int srow = t >> 1, spart = (t & 1) * 16;
  const unsigned short* Ab = A + (size_t)(rowbase + srow) * KDIM + spart;
  const unsigned short* Bb = Bt + (size_t)(colbase + srow) * KDIM + spart;
  unsigned short* lAw = lA + srow * SKP + spart;
  unsigned short* lBw = lB + srow * SKP + spart;

  f32x4 acc[4][4] = {};
  int4 ra0 = *(const int4*)(Ab);
  int4 ra1 = *(const int4*)(Ab + 8);
  int4 rb0 = *(const int4*)(Bb);
  int4 rb1 = *(const int4*)(Bb + 8);

  const int NT = KDIM / 32;
  for (int kt = 0; kt < NT; ++kt) {
    *(int4*)(lAw) = ra0; *(int4*)(lAw + 8) = ra1;
    *(int4*)(lBw) = rb0; *(int4*)(lBw + 8) = rb1;
    __syncthreads();
    if (kt + 1 < NT) {
      int kk = (kt + 1) * 32;
      ra0 = *(const int4*)(Ab + kk); ra1 = *(const int4*)(Ab + kk + 8);
      rb0 = *(const int4*)(Bb + kk); rb1 = *(const int4*)(Bb + kk + 8);
    }
    bf16x8 af[4], bfm[4];
    const unsigned short* lar = lA + (wrow + c) * SKP + g * 4;
    const unsigned short* lbr = lB + (wcol + c) * SKP + g * 4;
#pragma unroll
    for (int m = 0; m < 4; ++m) af[m] = ld_frag(lar + m * 16 * SKP);
#pragma unroll
    for (int n = 0; n < 4; ++n) bfm[n] = ld_frag(lbr + n * 16 * SKP);
#pragma unroll
    for (int m = 0; m < 4; ++m)
#pragma unroll
      for (int n = 0; n < 4; ++n)
        acc[m][n] = __builtin_amdgcn_mfma_f32_16x16x32_bf16(af[m], bfm[n], acc[m][n], 0, 0, 0);
    __syncthreads();
  }

  if (EPI == 0) {
#pragma unroll
    for (int m = 0; m < 4; ++m)
#pragma unroll
      for (int n = 0; n < 4; ++n)
#pragma unroll
        for (int i = 0; i < 4; ++i) {
          int R = rowbase + wrow + m * 16 + g * 4 + i;
          int Cc = colbase + wcol + n * 16 + c;
          outF[(size_t)R * 2048 + Cc] = acc[m][n][i];
        }
  } else {
#pragma unroll
    for (int m = 0; m < 4; ++m) {
#pragma unroll
      for (int n = 0; n < 4; ++n) {
#pragma unroll
        for (int i = 0; i < 4; ++i) {
          float val = acc[m][n][i];
          float partner = __shfl_xor(val, 1, 64);  // adjacent column = rope pair
          int R = rowbase + wrow + m * 16 + g * 4 + i;
          int Cc = colbase + wcol + n * 16 + c;
          int b = R >> 11, s = R & 2047;
          int d = Cc & 127;
          int j = d >> 1;
          float cs = cosT[s * 64 + j], sn = sinT[s * 64 + j];
          float ro = ((d & 1) == 0) ? (val * cs - partner * sn)
                                    : (partner * sn + val * cs);
          if (Cc < 2048) {  // q
            int h = Cc >> 7;
            qws[((size_t)(b * HH + h) * SS + s) * DD + d] = f2b(ro);
          } else if (Cc < 2560) {  // k (roped) -> d_out + bf16 ws
            int kvh = (Cc - 2048) >> 7;
            size_t idx = ((size_t)(b * KVH + kvh) * SS + s) * DD + d;
            koutF[idx] = ro;
            kws[idx] = f2b(ro);
          } else {  // v (raw) -> d_out + transposed bf16 ws
            int kvh = (Cc - 2560) >> 7;
            size_t idx = ((size_t)(b * KVH + kvh) * SS + s) * DD + d;
            voutF[idx] = val;
            vTws[((size_t)(b * KVH + kvh) * DD + d) * SS + s] = f2b(val);
          }
        }
      }
    }
  }
}

// Flash attention: each wave owns one 16-row Q block. Swapped QK^T so lane
// holds a full P-row; P lands in A-fragment layout for PV directly.
__global__ __launch_bounds__(256) void k_attn(const unsigned short* __restrict__ qws,
                                              const unsigned short* __restrict__ kws,
                                              const unsigned short* __restrict__ vT,
                                              unsigned short* __restrict__ aows) {
  const int lane = threadIdx.x & 63;
  const int wid = threadIdx.x >> 6;
  const int task = blockIdx.x * 4 + wid;
  const int qblk = 127 - (task & 127);  // long blocks first for load balance
  const int head = task >> 7;
  const int b = head >> 4, h = head & 15;
  const int kv = h >> 2;
  const int g = lane >> 4, c = lane & 15;
  const int q0 = qblk * 16;
  const float scale = 0.088388347648318447f;  // 1/sqrt(128)

  const unsigned short* qp = qws + ((size_t)(b * HH + h) * SS + q0 + c) * DD;
  bf16x8 qf[4];
#pragma unroll
  for (int ks = 0; ks < 4; ++ks) qf[ks] = ld_frag(qp + ks * 32 + g * 4);

  const unsigned short* kbase = kws + (size_t)(b * KVH + kv) * SS * DD;
  const unsigned short* vbase = vT + (size_t)(b * KVH + kv) * DD * SS;

  f32x4 o[8] = {};
  float mrow = -1e30f, lrow = 0.f;
  const int kend = q0 + 16;
  for (int kb = 0; kb < kend; kb += 32) {
    f32x4 st0 = {0.f, 0.f, 0.f, 0.f}, st1 = {0.f, 0.f, 0.f, 0.f};
    {
      const unsigned short* kp = kbase + (size_t)(kb + c) * DD;
#pragma unroll
      for (int ks = 0; ks < 4; ++ks)
        st0 = __builtin_amdgcn_mfma_f32_16x16x32_bf16(ld_frag(kp + ks * 32 + g * 4), qf[ks], st0, 0, 0, 0);
    }
    {
      const unsigned short* kp = kbase + (size_t)(kb + 16 + c) * DD;
#pragma unroll
      for (int ks = 0; ks < 4; ++ks)
        st1 = __builtin_amdgcn_mfma_f32_16x16x32_bf16(ld_frag(kp + ks * 32 + g * 4), qf[ks], st1, 0, 0, 0);
    }
    // lane holds S[q = q0+c][k = kb + 16*h2 + 4*g + i]
    float p[8];
    float pmax = -1e30f;
    const bool needMask = (kb + 32 > q0);
#pragma unroll
    for (int e = 0; e < 8; ++e) {
      int h2 = e >> 2, i = e & 3;
      float v = (h2 ? st1[i] : st0[i]) * scale;
      if (needMask) {
        int kg = kb + h2 * 16 + g * 4 + i;
        if (kg > q0 + c) v = -1e30f;
      }
      p[e] = v;
      pmax = fmaxf(pmax, v);
    }
    pmax = fmaxf(pmax, __shfl_xor(pmax, 16, 64));
    pmax = fmaxf(pmax, __shfl_xor(pmax, 32, 64));
    float mnew = fmaxf(mrow, pmax);
    float fac = __expf(mrow - mnew);
    float rsum = 0.f;
#pragma unroll
    for (int e = 0; e < 8; ++e) { p[e] = __expf(p[e] - mnew); rsum += p[e]; }
    rsum += __shfl_xor(rsum, 16, 64);
    rsum += __shfl_xor(rsum, 32, 64);
    lrow = lrow * fac + rsum;
    mrow = mnew;
    bf16x8 pf;
#pragma unroll
    for (int e = 0; e < 8; ++e) pf[e] = (short)f2b(p[e]);
    // rescale O (O-rows are g*4+i; factor lives in lane q)
    float fi0 = __shfl(fac, g * 4 + 0, 64);
    float fi1 = __shfl(fac, g * 4 + 1, 64);
    float fi2 = __shfl(fac, g * 4 + 2, 64);
    float fi3 = __shfl(fac, g * 4 + 3, 64);
#pragma unroll
    for (int db = 0; db < 8; ++db) {
      o[db][0] *= fi0; o[db][1] *= fi1; o[db][2] *= fi2; o[db][3] *= fi3;
    }
#pragma unroll
    for (int db = 0; db < 8; ++db) {
      const unsigned short* vp = vbase + (size_t)(db * 16 + c) * SS + kb + g * 4;
      o[db] = __builtin_amdgcn_mfma_f32_16x16x32_bf16(pf, ld_frag(vp), o[db], 0, 0, 0);
    }
  }
  float li0 = 1.f / __shfl(lrow, g * 4 + 0, 64);
  float li1 = 1.f / __shfl(lrow, g * 4 + 1, 64);
  float li2 = 1.f / __shfl(lrow, g * 4 + 2, 64);
  float li3 = 1.f / __shfl(lrow, g * 4 + 3, 64);
  unsigned short* op = aows + ((size_t)b * SS + q0) * (HH * DD) + h * DD;
#pragma unroll
  for (int db = 0; db < 8; ++db) {
    op[(size_t)(g * 4 + 0) * 2048 + db * 16 + c] = f2b(o[db][0] * li0);
    op[(size_t)(g * 4 + 1) * 2048 + db * 16 + c] = f2b(o[db][1] * li1);
    op[(size_t)(g * 4 + 2) * 2048 + db * 16 + c] = f2b(o[db][2] * li2);
    op[(size_t)(g * 4 + 3) * 2048 + db * 16 + c] = f2b(o[db][3] * li3);
  }
}

extern "C" void kernel_launch(void* const* d_in, const int* in_sizes, int n_in,
                              void* d_out, int out_size, void* d_ws, size_t ws_size,
                              hipStream_t stream) {
  (void)in_sizes; (void)n_in; (void)out_size; (void)ws_size;
  const float* x  = (const float*)d_in[0];
  const float* fc = (const float*)d_in[1];
  const float* fs = (const float*)d_in[2];
  const float* wq = (const float*)d_in[3];
  const float* wk = (const float*)d_in[4];
  const float* wv = (const float*)d_in[5];
  const float* wo = (const float*)d_in[6];
  float* out = (float*)d_out;
  float* koutF = out + (size_t)BB * SS * HIDD;                  // (B,KV,S,D)
  float* voutF = koutF + (size_t)BB * KVH * SS * DD;            // (B,KV,S,D)

  unsigned short* wcatT = (unsigned short*)d_ws;                // (3072, 2048)
  unsigned short* woT   = wcatT + (size_t)3072 * 2048;          // (2048, 2048)
  unsigned short* xbf   = woT + (size_t)2048 * 2048;            // (4096, 2048)
  unsigned short* qws   = xbf + (size_t)4096 * 2048;            // (B,H,S,D)
  unsigned short* kws   = qws + (size_t)BB * HH * SS * DD;      // (B,KV,S,D)
  unsigned short* vTws  = kws + (size_t)BB * KVH * SS * DD;     // (B,KV,D,S)
  unsigned short* aows  = vTws + (size_t)BB * KVH * DD * SS;    // (B*S, H*D)

  k_convert<<<2048, 256, 0, stream>>>(x, xbf, (int)((size_t)4096 * 2048 / 4));
  dim3 tb(32, 8);
  k_transpose<<<dim3(64, 64), tb, 0, stream>>>(wq, wcatT, 2048, 2048);
  k_transpose<<<dim3(16, 64), tb, 0, stream>>>(wk, wcatT + (size_t)2048 * 2048, 2048, 512);
  k_transpose<<<dim3(16, 64), tb, 0, stream>>>(wv, wcatT + (size_t)2560 * 2048, 2048, 512);
  k_transpose<<<dim3(64, 64), tb, 0, stream>>>(wo, woT, 2048, 2048);

  k_gemm<1><<<dim3(32, 24), 256, 0, stream>>>(xbf, wcatT, nullptr, qws, kws, vTws,
                                              koutF, voutF, fc, fs);
  k_attn<<<1024, 256, 0, stream>>>(qws, kws, vTws, aows);
  k_gemm<0><<<dim3(32, 16), 256, 0, stream>>>(aows, woT, out, nullptr, nullptr, nullptr,
                                              nullptr, nullptr, nullptr, nullptr);
}

// Round 2
// 306.160 us; speedup vs baseline: 3.4743x; 3.4743x over previous
//
#include <hip/hip_runtime.h>
#include <stdint.h>

// Problem constants
#define BB 2
#define SS 2048
#define HIDD 2048
#define HH 16
#define KVH 4
#define DD 128
#define KDIM 2048

typedef short bf16x4 __attribute__((ext_vector_type(4)));
typedef short bf16x8 __attribute__((ext_vector_type(8)));
typedef float f32x4 __attribute__((ext_vector_type(4)));

__device__ __forceinline__ unsigned short f2b(float f) {
  union { float f; unsigned u; } v; v.f = f;
  unsigned r = v.u + 0x7FFFu + ((v.u >> 16) & 1u);
  return (unsigned short)(r >> 16);
}

// Load an 8-element bf16 MFMA fragment from global: elems 0-3 at p[0..3], 4-7 at p[16..19]
__device__ __forceinline__ bf16x8 ld_frag(const unsigned short* p) {
  union { bf16x8 v8; bf16x4 v4[2]; } u;
  u.v4[0] = *reinterpret_cast<const bf16x4*>(p);
  u.v4[1] = *reinterpret_cast<const bf16x4*>(p + 16);
  return u.v8;
}

// K tile in LDS: [64 rows][128 elems], 256B rows, swizzle byte ^= (row&7)<<4
__device__ __forceinline__ bf16x8 ldK(const char* lds, int row, int elem) {
  union { bf16x8 v8; int2 h[2]; } u;
  int base = row * 256 + elem * 2;
  int sw = (row & 7) << 4;
  u.h[0] = *reinterpret_cast<const int2*>(lds + ((base) ^ sw));
  u.h[1] = *reinterpret_cast<const int2*>(lds + ((base + 32) ^ sw));
  return u.v8;
}

// V^T tile in LDS: [128 d-rows][64 elems], 128B rows, swizzle byte ^= (row&15)<<3
__device__ __forceinline__ bf16x8 ldV(const char* lds, int row, int elem) {
  union { bf16x8 v8; int2 h[2]; } u;
  int base = row * 128 + elem * 2;
  int sw = (row & 15) << 3;
  u.h[0] = *reinterpret_cast<const int2*>(lds + ((base) ^ sw));
  u.h[1] = *reinterpret_cast<const int2*>(lds + ((base + 32) ^ sw));
  return u.v8;
}

__global__ __launch_bounds__(256) void k_convert(const float* __restrict__ in,
                                                 unsigned short* __restrict__ out, int n4) {
  int i = blockIdx.x * 256 + threadIdx.x;
  int stride = gridDim.x * 256;
  for (; i < n4; i += stride) {
    float4 v = reinterpret_cast<const float4*>(in)[i];
    ushort4 o;
    o.x = f2b(v.x); o.y = f2b(v.y); o.z = f2b(v.z); o.w = f2b(v.w);
    reinterpret_cast<ushort4*>(out)[i] = o;
  }
}

// in: (K,N) fp32 row-major -> out: (N,K) bf16 row-major
__global__ __launch_bounds__(256) void k_transpose(const float* __restrict__ in,
                                                   unsigned short* __restrict__ out,
                                                   int K, int N) {
  __shared__ float tile[32][33];
  int n0 = blockIdx.x * 32, k0 = blockIdx.y * 32;
  int tx = threadIdx.x, ty = threadIdx.y;
#pragma unroll
  for (int j = 0; j < 32; j += 8)
    tile[ty + j][tx] = in[(size_t)(k0 + ty + j) * N + n0 + tx];
  __syncthreads();
#pragma unroll
  for (int j = 0; j < 32; j += 8)
    out[(size_t)(n0 + ty + j) * K + k0 + tx] = f2b(tile[tx][ty + j]);
}

// C = A(M x K) * Bt(N x K)^T, bf16 inputs, 128x128 tile, 4 waves, 4x4 frags each.
template <int EPI>
__global__ __launch_bounds__(256) void k_gemm(
    const unsigned short* __restrict__ A, const unsigned short* __restrict__ Bt,
    float* __restrict__ outF, unsigned short* __restrict__ qws,
    unsigned short* __restrict__ kws, unsigned short* __restrict__ vTws,
    float* __restrict__ koutF, float* __restrict__ voutF,
    const float* __restrict__ cosT, const float* __restrict__ sinT) {
  constexpr int SKP = 40;
  __shared__ __align__(16) unsigned short lA[128 * SKP];
  __shared__ __align__(16) unsigned short lB[128 * SKP];
  const int rowbase = blockIdx.x * 128;
  const int colbase = blockIdx.y * 128;
  const int t = threadIdx.x;
  const int wid = t >> 6, lane = t & 63;
  const int g = lane >> 4, c = lane & 15;
  const int wrow = (wid >> 1) * 64, wcol = (wid & 1) * 64;

  const int srow = t >> 1, spart = (t & 1) * 16;
  const unsigned short* Ab = A + (size_t)(rowbase + srow) * KDIM + spart;
  const unsigned short* Bb = Bt + (size_t)(colbase + srow) * KDIM + spart;
  unsigned short* lAw = lA + srow * SKP + spart;
  unsigned short* lBw = lB + srow * SKP + spart;

  f32x4 acc[4][4] = {};
  int4 ra0 = *(const int4*)(Ab);
  int4 ra1 = *(const int4*)(Ab + 8);
  int4 rb0 = *(const int4*)(Bb);
  int4 rb1 = *(const int4*)(Bb + 8);

  const int NT = KDIM / 32;
  for (int kt = 0; kt < NT; ++kt) {
    *(int4*)(lAw) = ra0; *(int4*)(lAw + 8) = ra1;
    *(int4*)(lBw) = rb0; *(int4*)(lBw + 8) = rb1;
    __syncthreads();
    if (kt + 1 < NT) {
      int kk = (kt + 1) * 32;
      ra0 = *(const int4*)(Ab + kk); ra1 = *(const int4*)(Ab + kk + 8);
      rb0 = *(const int4*)(Bb + kk); rb1 = *(const int4*)(Bb + kk + 8);
    }
    bf16x8 af[4], bfm[4];
    const unsigned short* lar = lA + (wrow + c) * SKP + g * 4;
    const unsigned short* lbr = lB + (wcol + c) * SKP + g * 4;
#pragma unroll
    for (int m = 0; m < 4; ++m) af[m] = ld_frag(lar + m * 16 * SKP);
#pragma unroll
    for (int n = 0; n < 4; ++n) bfm[n] = ld_frag(lbr + n * 16 * SKP);
#pragma unroll
    for (int m = 0; m < 4; ++m)
#pragma unroll
      for (int n = 0; n < 4; ++n)
        acc[m][n] = __builtin_amdgcn_mfma_f32_16x16x32_bf16(af[m], bfm[n], acc[m][n], 0, 0, 0);
    __syncthreads();
  }

  if (EPI == 0) {
#pragma unroll
    for (int m = 0; m < 4; ++m)
#pragma unroll
      for (int n = 0; n < 4; ++n)
#pragma unroll
        for (int i = 0; i < 4; ++i) {
          int R = rowbase + wrow + m * 16 + g * 4 + i;
          int Cc = colbase + wcol + n * 16 + c;
          outF[(size_t)R * 2048 + Cc] = acc[m][n][i];
        }
  } else {
#pragma unroll
    for (int m = 0; m < 4; ++m) {
#pragma unroll
      for (int n = 0; n < 4; ++n) {
#pragma unroll
        for (int i = 0; i < 4; ++i) {
          float val = acc[m][n][i];
          float partner = __shfl_xor(val, 1, 64);
          int R = rowbase + wrow + m * 16 + g * 4 + i;
          int Cc = colbase + wcol + n * 16 + c;
          int b = R >> 11, s = R & 2047;
          int d = Cc & 127;
          int j = d >> 1;
          float cs = cosT[s * 64 + j], sn = sinT[s * 64 + j];
          float ro = ((d & 1) == 0) ? (val * cs - partner * sn)
                                    : (partner * sn + val * cs);
          if (Cc < 2048) {
            int h = Cc >> 7;
            qws[((size_t)(b * HH + h) * SS + s) * DD + d] = f2b(ro);
          } else if (Cc < 2560) {
            int kvh = (Cc - 2048) >> 7;
            size_t idx = ((size_t)(b * KVH + kvh) * SS + s) * DD + d;
            koutF[idx] = ro;
            kws[idx] = f2b(ro);
          } else {
            int kvh = (Cc - 2560) >> 7;
            size_t idx = ((size_t)(b * KVH + kvh) * SS + s) * DD + d;
            voutF[idx] = val;
            vTws[((size_t)(b * KVH + kvh) * DD + d) * SS + s] = f2b(val);
          }
        }
      }
    }
  }
}

// Flash attention, block-cooperative:
//   block = 4 waves = one head x 64 q-rows (wave w owns rows q0+16w..+15)
//   per 64-wide KV tile: K[64][128] + V^T[128][64] staged in LDS (32 KB, swizzled),
//   async-stage split: issue next tile's global loads before compute, ds_write after.
__global__ __launch_bounds__(256) void k_attn(const unsigned short* __restrict__ qws,
                                              const unsigned short* __restrict__ kws,
                                              const unsigned short* __restrict__ vT,
                                              unsigned short* __restrict__ aows) {
  __shared__ __align__(16) char lK[64 * 256];   // 16 KB
  __shared__ __align__(16) char lV[128 * 128];  // 16 KB
  const int lane = threadIdx.x & 63;
  const int w = threadIdx.x >> 6;
  const int bid = blockIdx.x;
  // XCD-aware: one KV head per XCD (1 MB K+V resident in its L2); longest qblk first.
  const int head = (bid & 7) * 4 + ((bid >> 3) & 3);
  const int qblk = 31 - (bid >> 5);
  const int b = head >> 4, h = head & 15;
  const int kv = h >> 2;
  const int g = lane >> 4, c = lane & 15;
  const int q0 = qblk * 64;
  const int qr0 = q0 + w * 16;
  const float scale = 0.088388347648318447f;  // 1/sqrt(128)

  const unsigned short* qp = qws + ((size_t)(b * HH + h) * SS + qr0 + c) * DD;
  bf16x8 qf[4];
#pragma unroll
  for (int ks = 0; ks < 4; ++ks) qf[ks] = ld_frag(qp + ks * 32 + g * 4);

  const unsigned short* kbase = kws + (size_t)(b * KVH + kv) * SS * DD;
  const unsigned short* vbase = vT + (size_t)(b * KVH + kv) * DD * SS;

  const int trow = threadIdx.x >> 4;  // 0..15
  const int tcol = threadIdx.x & 15;  // 0..15

  int4 kst[4];
  int2 vst[8];

  auto ISSUE = [&](int tt) {
    const int kb2 = tt * 64;
#pragma unroll
    for (int r = 0; r < 4; ++r)
      kst[r] = *reinterpret_cast<const int4*>(kbase + (size_t)(kb2 + r * 16 + trow) * DD + tcol * 8);
#pragma unroll
    for (int r = 0; r < 8; ++r)
      vst[r] = *reinterpret_cast<const int2*>(vbase + (size_t)(r * 16 + trow) * SS + kb2 + tcol * 4);
  };
  auto WRITE = [&]() {
#pragma unroll
    for (int r = 0; r < 4; ++r) {
      int row = r * 16 + trow;
      *reinterpret_cast<int4*>(lK + ((row * 256 + tcol * 16) ^ ((row & 7) << 4))) = kst[r];
    }
#pragma unroll
    for (int r = 0; r < 8; ++r) {
      int row = r * 16 + trow;
      *reinterpret_cast<int2*>(lV + ((row * 128 + tcol * 8) ^ ((row & 15) << 3))) = vst[r];
    }
  };

  f32x4 o[8] = {};
  float mrow = -1e30f, lrow = 0.f;
  const int nt = qblk + 1;

  ISSUE(0);
  WRITE();
  __syncthreads();

  for (int t = 0; t < nt; ++t) {
    const bool more = (t + 1 < nt);
    if (more) ISSUE(t + 1);
    const bool lastT = (t == nt - 1);

    // QK^T: st[s] holds S[q=qr0+c][k = t*64 + s*16 + g*4 + e]
    f32x4 st[4] = {};
    __builtin_amdgcn_s_setprio(1);
#pragma unroll
    for (int s = 0; s < 4; ++s)
#pragma unroll
      for (int ks = 0; ks < 4; ++ks)
        st[s] = __builtin_amdgcn_mfma_f32_16x16x32_bf16(
            ldK(lK, s * 16 + c, ks * 32 + g * 4), qf[ks], st[s], 0, 0, 0);
    __builtin_amdgcn_s_setprio(0);

    float p[16];
    float pmax = -1e30f;
#pragma unroll
    for (int s = 0; s < 4; ++s)
#pragma unroll
      for (int e = 0; e < 4; ++e) {
        float v = st[s][e] * scale;
        if (lastT && (s * 16 + g * 4 + e > w * 16 + c)) v = -1e30f;
        p[s * 4 + e] = v;
        pmax = fmaxf(pmax, v);
      }
    pmax = fmaxf(pmax, __shfl_xor(pmax, 16, 64));
    pmax = fmaxf(pmax, __shfl_xor(pmax, 32, 64));
    float mnew = fmaxf(mrow, pmax);
    float fac = __expf(mrow - mnew);
    float rsum = 0.f;
#pragma unroll
    for (int e = 0; e < 16; ++e) { p[e] = __expf(p[e] - mnew); rsum += p[e]; }
    rsum += __shfl_xor(rsum, 16, 64);
    rsum += __shfl_xor(rsum, 32, 64);
    lrow = lrow * fac + rsum;
    mrow = mnew;

    bf16x8 pf[2];
#pragma unroll
    for (int kk = 0; kk < 2; ++kk)
#pragma unroll
      for (int e = 0; e < 8; ++e) pf[kk][e] = (short)f2b(p[kk * 8 + e]);

    float fi0 = __shfl(fac, g * 4 + 0, 64);
    float fi1 = __shfl(fac, g * 4 + 1, 64);
    float fi2 = __shfl(fac, g * 4 + 2, 64);
    float fi3 = __shfl(fac, g * 4 + 3, 64);
#pragma unroll
    for (int db = 0; db < 8; ++db) {
      o[db][0] *= fi0; o[db][1] *= fi1; o[db][2] *= fi2; o[db][3] *= fi3;
    }

    __builtin_amdgcn_s_setprio(1);
#pragma unroll
    for (int db = 0; db < 8; ++db)
#pragma unroll
      for (int kk = 0; kk < 2; ++kk)
        o[db] = __builtin_amdgcn_mfma_f32_16x16x32_bf16(
            pf[kk], ldV(lV, db * 16 + c, kk * 32 + g * 4), o[db], 0, 0, 0);
    __builtin_amdgcn_s_setprio(0);

    __syncthreads();
    if (more) {
      WRITE();
      __syncthreads();
    }
  }

  float li0 = 1.f / __shfl(lrow, g * 4 + 0, 64);
  float li1 = 1.f / __shfl(lrow, g * 4 + 1, 64);
  float li2 = 1.f / __shfl(lrow, g * 4 + 2, 64);
  float li3 = 1.f / __shfl(lrow, g * 4 + 3, 64);
  unsigned short* op = aows + ((size_t)b * SS + qr0) * (HH * DD) + h * DD;
#pragma unroll
  for (int db = 0; db < 8; ++db) {
    op[(size_t)(g * 4 + 0) * 2048 + db * 16 + c] = f2b(o[db][0] * li0);
    op[(size_t)(g * 4 + 1) * 2048 + db * 16 + c] = f2b(o[db][1] * li1);
    op[(size_t)(g * 4 + 2) * 2048 + db * 16 + c] = f2b(o[db][2] * li2);
    op[(size_t)(g * 4 + 3) * 2048 + db * 16 + c] = f2b(o[db][3] * li3);
  }
}

extern "C" void kernel_launch(void* const* d_in, const int* in_sizes, int n_in,
                              void* d_out, int out_size, void* d_ws, size_t ws_size,
                              hipStream_t stream) {
  (void)in_sizes; (void)n_in; (void)out_size; (void)ws_size;
  const float* x  = (const float*)d_in[0];
  const float* fc = (const float*)d_in[1];
  const float* fs = (const float*)d_in[2];
  const float* wq = (const float*)d_in[3];
  const float* wk = (const float*)d_in[4];
  const float* wv = (const float*)d_in[5];
  const float* wo = (const float*)d_in[6];
  float* out = (float*)d_out;
  float* koutF = out + (size_t)BB * SS * HIDD;                  // (B,KV,S,D)
  float* voutF = koutF + (size_t)BB * KVH * SS * DD;            // (B,KV,S,D)

  unsigned short* wcatT = (unsigned short*)d_ws;                // (3072, 2048)
  unsigned short* woT   = wcatT + (size_t)3072 * 2048;          // (2048, 2048)
  unsigned short* xbf   = woT + (size_t)2048 * 2048;            // (4096, 2048)
  unsigned short* qws   = xbf + (size_t)4096 * 2048;            // (B,H,S,D)
  unsigned short* kws   = qws + (size_t)BB * HH * SS * DD;      // (B,KV,S,D)
  unsigned short* vTws  = kws + (size_t)BB * KVH * SS * DD;     // (B,KV,D,S)
  unsigned short* aows  = vTws + (size_t)BB * KVH * DD * SS;    // (B*S, H*D)

  k_convert<<<2048, 256, 0, stream>>>(x, xbf, (int)((size_t)4096 * 2048 / 4));
  dim3 tb(32, 8);
  k_transpose<<<dim3(64, 64), tb, 0, stream>>>(wq, wcatT, 2048, 2048);
  k_transpose<<<dim3(16, 64), tb, 0, stream>>>(wk, wcatT + (size_t)2048 * 2048, 2048, 512);
  k_transpose<<<dim3(16, 64), tb, 0, stream>>>(wv, wcatT + (size_t)2560 * 2048, 2048, 512);
  k_transpose<<<dim3(64, 64), tb, 0, stream>>>(wo, woT, 2048, 2048);

  k_gemm<1><<<dim3(32, 24), 256, 0, stream>>>(xbf, wcatT, nullptr, qws, kws, vTws,
                                              koutF, voutF, fc, fs);
  k_attn<<<1024, 256, 0, stream>>>(qws, kws, vTws, aows);
  k_gemm<0><<<dim3(32, 16), 256, 0, stream>>>(aows, woT, out, nullptr, nullptr, nullptr,
                                              nullptr, nullptr, nullptr, nullptr);
}

// Round 3
// 278.477 us; speedup vs baseline: 3.8197x; 1.0994x over previous
//
#include <hip/hip_runtime.h>
#include <stdint.h>

// Problem constants
#define BB 2
#define SS 2048
#define HIDD 2048
#define HH 16
#define KVH 4
#define DD 128
#define KDIM 2048

typedef short bf16x4 __attribute__((ext_vector_type(4)));
typedef short bf16x8 __attribute__((ext_vector_type(8)));
typedef float f32x4 __attribute__((ext_vector_type(4)));
typedef float f32x16 __attribute__((ext_vector_type(16)));

__device__ __forceinline__ unsigned short f2b(float f) {
  union { float f; unsigned u; } v; v.f = f;
  unsigned r = v.u + 0x7FFFu + ((v.u >> 16) & 1u);
  return (unsigned short)(r >> 16);
}

__device__ __forceinline__ unsigned cvtpk_bf16(float a, float b) {
  unsigned r;
  asm("v_cvt_pk_bf16_f32 %0, %1, %2" : "=v"(r) : "v"(a), "v"(b));
  return r;
}

// Load an 8-element bf16 MFMA fragment (16x16x32): elems 0-3 at p[0..3], 4-7 at p[16..19]
__device__ __forceinline__ bf16x8 ld_frag(const unsigned short* p) {
  union { bf16x8 v8; bf16x4 v4[2]; } u;
  u.v4[0] = *reinterpret_cast<const bf16x4*>(p);
  u.v4[1] = *reinterpret_cast<const bf16x4*>(p + 16);
  return u.v8;
}

// 16B LDS tile read (pre-swizzled offset computed at call site)
__device__ __forceinline__ bf16x8 ldT(const char* lds, int byteoff) {
  union { bf16x8 v; int4 q; } u;
  u.q = *reinterpret_cast<const int4*>(lds + byteoff);
  return u.v;
}

__global__ __launch_bounds__(256) void k_convert(const float* __restrict__ in,
                                                 unsigned short* __restrict__ out, int n4) {
  int i = blockIdx.x * 256 + threadIdx.x;
  int stride = gridDim.x * 256;
  for (; i < n4; i += stride) {
    float4 v = reinterpret_cast<const float4*>(in)[i];
    ushort4 o;
    o.x = f2b(v.x); o.y = f2b(v.y); o.z = f2b(v.z); o.w = f2b(v.w);
    reinterpret_cast<ushort4*>(out)[i] = o;
  }
}

// in: (K,N) fp32 row-major -> out: (N,K) bf16 row-major
__global__ __launch_bounds__(256) void k_transpose(const float* __restrict__ in,
                                                   unsigned short* __restrict__ out,
                                                   int K, int N) {
  __shared__ float tile[32][33];
  int n0 = blockIdx.x * 32, k0 = blockIdx.y * 32;
  int tx = threadIdx.x, ty = threadIdx.y;
#pragma unroll
  for (int j = 0; j < 32; j += 8)
    tile[ty + j][tx] = in[(size_t)(k0 + ty + j) * N + n0 + tx];
  __syncthreads();
#pragma unroll
  for (int j = 0; j < 32; j += 8)
    out[(size_t)(n0 + ty + j) * K + k0 + tx] = f2b(tile[tx][ty + j]);
}

// C = A(M x K) * Bt(N x K)^T, bf16 inputs, 128x128 tile, 4 waves, 4x4 frags each.
template <int EPI>
__global__ __launch_bounds__(256) void k_gemm(
    const unsigned short* __restrict__ A, const unsigned short* __restrict__ Bt,
    float* __restrict__ outF, unsigned short* __restrict__ qws,
    unsigned short* __restrict__ kws, unsigned short* __restrict__ vTws,
    float* __restrict__ koutF, float* __restrict__ voutF,
    const float* __restrict__ cosT, const float* __restrict__ sinT) {
  constexpr int SKP = 40;
  __shared__ __align__(16) unsigned short lA[128 * SKP];
  __shared__ __align__(16) unsigned short lB[128 * SKP];
  const int rowbase = blockIdx.x * 128;
  const int colbase = blockIdx.y * 128;
  const int t = threadIdx.x;
  const int wid = t >> 6, lane = t & 63;
  const int g = lane >> 4, c = lane & 15;
  const int wrow = (wid >> 1) * 64, wcol = (wid & 1) * 64;

  const int srow = t >> 1, spart = (t & 1) * 16;
  const unsigned short* Ab = A + (size_t)(rowbase + srow) * KDIM + spart;
  const unsigned short* Bb = Bt + (size_t)(colbase + srow) * KDIM + spart;
  unsigned short* lAw = lA + srow * SKP + spart;
  unsigned short* lBw = lB + srow * SKP + spart;

  f32x4 acc[4][4] = {};
  int4 ra0 = *(const int4*)(Ab);
  int4 ra1 = *(const int4*)(Ab + 8);
  int4 rb0 = *(const int4*)(Bb);
  int4 rb1 = *(const int4*)(Bb + 8);

  const int NT = KDIM / 32;
  for (int kt = 0; kt < NT; ++kt) {
    *(int4*)(lAw) = ra0; *(int4*)(lAw + 8) = ra1;
    *(int4*)(lBw) = rb0; *(int4*)(lBw + 8) = rb1;
    __syncthreads();
    if (kt + 1 < NT) {
      int kk = (kt + 1) * 32;
      ra0 = *(const int4*)(Ab + kk); ra1 = *(const int4*)(Ab + kk + 8);
      rb0 = *(const int4*)(Bb + kk); rb1 = *(const int4*)(Bb + kk + 8);
    }
    bf16x8 af[4], bfm[4];
    const unsigned short* lar = lA + (wrow + c) * SKP + g * 4;
    const unsigned short* lbr = lB + (wcol + c) * SKP + g * 4;
#pragma unroll
    for (int m = 0; m < 4; ++m) af[m] = ld_frag(lar + m * 16 * SKP);
#pragma unroll
    for (int n = 0; n < 4; ++n) bfm[n] = ld_frag(lbr + n * 16 * SKP);
#pragma unroll
    for (int m = 0; m < 4; ++m)
#pragma unroll
      for (int n = 0; n < 4; ++n)
        acc[m][n] = __builtin_amdgcn_mfma_f32_16x16x32_bf16(af[m], bfm[n], acc[m][n], 0, 0, 0);
    __syncthreads();
  }

  if (EPI == 0) {
#pragma unroll
    for (int m = 0; m < 4; ++m)
#pragma unroll
      for (int n = 0; n < 4; ++n)
#pragma unroll
        for (int i = 0; i < 4; ++i) {
          int R = rowbase + wrow + m * 16 + g * 4 + i;
          int Cc = colbase + wcol + n * 16 + c;
          outF[(size_t)R * 2048 + Cc] = acc[m][n][i];
        }
  } else {
#pragma unroll
    for (int m = 0; m < 4; ++m) {
#pragma unroll
      for (int n = 0; n < 4; ++n) {
#pragma unroll
        for (int i = 0; i < 4; ++i) {
          float val = acc[m][n][i];
          float partner = __shfl_xor(val, 1, 64);
          int R = rowbase + wrow + m * 16 + g * 4 + i;
          int Cc = colbase + wcol + n * 16 + c;
          int b = R >> 11, s = R & 2047;
          int d = Cc & 127;
          int j = d >> 1;
          float cs = cosT[s * 64 + j], sn = sinT[s * 64 + j];
          float ro = ((d & 1) == 0) ? (val * cs - partner * sn)
                                    : (partner * sn + val * cs);
          if (Cc < 2048) {
            int h = Cc >> 7;
            qws[((size_t)(b * HH + h) * SS + s) * DD + d] = f2b(ro);
          } else if (Cc < 2560) {
            int kvh = (Cc - 2048) >> 7;
            size_t idx = ((size_t)(b * KVH + kvh) * SS + s) * DD + d;
            koutF[idx] = ro;
            kws[idx] = f2b(ro);
          } else {
            int kvh = (Cc - 2560) >> 7;
            size_t idx = ((size_t)(b * KVH + kvh) * SS + s) * DD + d;
            voutF[idx] = val;
            vTws[((size_t)(b * KVH + kvh) * DD + d) * SS + s] = f2b(val);
          }
        }
      }
    }
  }
}

// Flash attention, 32x32 MFMA, double-swapped operands.
//   block = 4 waves x 32 q-rows = 128 q-rows, one (b,h).
//   Per KVBLK=64 tile: K[64][128] + V^T[128][64] staged in LDS, half-interleaved
//   (frag = contiguous 16B) + XOR((row&15)<<4) swizzle, double-buffered (64KB).
//   QK^T = mfma(K, Q): lane owns q = lane&31; softmax in-register (2 shuffles);
//   PV = mfma(V^T, P): P fragment == S registers in-lane (zero shuffles).
__global__ __launch_bounds__(256, 2) void k_attn(const unsigned short* __restrict__ qws,
                                                 const unsigned short* __restrict__ kws,
                                                 const unsigned short* __restrict__ vT,
                                                 unsigned short* __restrict__ aows) {
  __shared__ __align__(16) char lds[2][32768];  // per buf: K 16KB | V 16KB
  const int tid = threadIdx.x;
  const int lane = tid & 63;
  const int w = tid >> 6;
  const int lq = lane & 31;   // this lane's q-column
  const int hi = lane >> 5;   // k-parity half

  // mapping: bid<256 -> chunks 15..8, bid>=256 -> chunks 0..7 (pairs long+short per CU)
  const int bid = blockIdx.x;
  const int chunk = (bid < 256) ? (15 - (bid >> 5)) : ((bid - 256) >> 5);
  const int head = bid & 31;
  const int b = head >> 4, h = head & 15;
  const int kv = h >> 2;
  const int q0 = chunk * 128;
  const int q0w = q0 + w * 32;
  const int qg = q0w + lq;
  const int NT = chunk * 2 + 2;
  const float cl2 = 0.12751743f;  // (1/sqrt(128)) * log2(e)

  // Q fragments: qf[ks] elem e: d = ks*16 + hi*4 + (e&3) + 8*(e>>2)
  const unsigned short* qp = qws + ((size_t)(b * HH + h) * SS + qg) * DD;
  bf16x8 qf[8];
#pragma unroll
  for (int ks = 0; ks < 8; ++ks) {
    union { bf16x8 v8; bf16x4 v4[2]; } u;
    const unsigned short* p = qp + ks * 16 + hi * 4;
    u.v4[0] = *reinterpret_cast<const bf16x4*>(p);
    u.v4[1] = *reinterpret_cast<const bf16x4*>(p + 8);
    qf[ks] = u.v8;
  }

  const unsigned short* kbase = kws + (size_t)(b * KVH + kv) * SS * DD;
  const unsigned short* vbase = vT + (size_t)(b * KVH + kv) * DD * SS;

  // staging assignment
  const int krow = tid >> 2, kslB = tid & 3;   // K: 64 rows x 16 slots(16B)
  const int vrow = tid >> 1, vslB = tid & 1;   // V: 128 rows x 8 slots(16B)
  int2 kreg[8], vreg[8];

  auto ISSUE = [&](int t) {
    const int kb = t * 64;
#pragma unroll
    for (int ss = 0; ss < 4; ++ss) {
      int sl = kslB + ss * 4, ks = sl >> 1, h2 = sl & 1;
      const unsigned short* src = kbase + (size_t)(kb + krow) * DD + ks * 16 + h2 * 4;
      kreg[2 * ss]     = *reinterpret_cast<const int2*>(src);
      kreg[2 * ss + 1] = *reinterpret_cast<const int2*>(src + 8);
    }
#pragma unroll
    for (int ss = 0; ss < 4; ++ss) {
      int sl = vslB + ss * 2, kk = sl >> 1, h2 = sl & 1;
      const unsigned short* src = vbase + (size_t)vrow * SS + kb + kk * 16 + h2 * 4;
      vreg[2 * ss]     = *reinterpret_cast<const int2*>(src);
      vreg[2 * ss + 1] = *reinterpret_cast<const int2*>(src + 8);
    }
  };
  auto WRITE = [&](int buf) {
    char* lK = lds[buf];
    char* lV = lds[buf] + 16384;
#pragma unroll
    for (int ss = 0; ss < 4; ++ss) {
      int sl = kslB + ss * 4, ks = sl >> 1, h2 = sl & 1;
      int off = (krow * 256 + ks * 32 + h2 * 16) ^ ((krow & 15) << 4);
      int4 wv; wv.x = kreg[2*ss].x; wv.y = kreg[2*ss].y; wv.z = kreg[2*ss+1].x; wv.w = kreg[2*ss+1].y;
      *reinterpret_cast<int4*>(lK + off) = wv;
    }
#pragma unroll
    for (int ss = 0; ss < 4; ++ss) {
      int sl = vslB + ss * 2, kk = sl >> 1, h2 = sl & 1;
      int off = (vrow * 128 + kk * 32 + h2 * 16) ^ ((vrow & 15) << 4);
      int4 wv; wv.x = vreg[2*ss].x; wv.y = vreg[2*ss].y; wv.z = vreg[2*ss+1].x; wv.w = vreg[2*ss+1].y;
      *reinterpret_cast<int4*>(lV + off) = wv;
    }
  };

  f32x16 o[4] = {};
  float mrow = -1e30f, lrow = 0.f;

  ISSUE(0);
  WRITE(0);
  __syncthreads();

  for (int t = 0; t < NT; ++t) {
    const bool more = (t + 1 < NT);
    if (more) ISSUE(t + 1);

    if (t * 64 <= q0w + 31) {  // wave has live rows in this tile
      const char* lK = lds[t & 1];
      const char* lV = lds[t & 1] + 16384;
      const int rowK = lq;  // K-tile row base (mf*32 added below)
      const int swz = ((lq & 15) << 4);

      f32x16 s[2];
      __builtin_amdgcn_s_setprio(1);
#pragma unroll
      for (int mf = 0; mf < 2; ++mf) {
        f32x16 acc = {};
#pragma unroll
        for (int ks = 0; ks < 8; ++ks) {
          int off = ((mf * 32 + rowK) * 256 + ks * 32 + hi * 16) ^ swz;
          acc = __builtin_amdgcn_mfma_f32_32x32x16_bf16(ldT(lK, off), qf[ks], acc, 0, 0, 0);
        }
        s[mf] = acc;
      }
      __builtin_amdgcn_s_setprio(0);

      // softmax (log2 domain), lane owns q-row qg; k = t*64 + mf*32 + (r&3)+8*(r>>2)+4*hi
      const bool needMask = (t * 64 + 63) > q0w;
      const int kq = t * 64 + 4 * hi - qg;
      float p[32];
      float rowmax = -1e30f;
#pragma unroll
      for (int mf = 0; mf < 2; ++mf)
#pragma unroll
        for (int r = 0; r < 16; ++r) {
          float v = s[mf][r] * cl2;
          if (needMask) {
            int kl = mf * 32 + (r & 3) + 8 * (r >> 2);
            if (kq + kl > 0) v = -1e30f;
          }
          p[mf * 16 + r] = v;
          rowmax = fmaxf(rowmax, v);
        }
      rowmax = fmaxf(rowmax, __shfl_xor(rowmax, 32, 64));

      if (__any(rowmax > mrow + 8.f)) {  // T13 defer-max
        float mnew = fmaxf(mrow, rowmax);
        float fac = exp2f(mrow - mnew);
        mrow = mnew;
        lrow *= fac;
#pragma unroll
        for (int d0 = 0; d0 < 4; ++d0)
#pragma unroll
          for (int r = 0; r < 16; ++r) o[d0][r] *= fac;
      }

      float rsum = 0.f;
#pragma unroll
      for (int e = 0; e < 32; ++e) { p[e] = exp2f(p[e] - mrow); rsum += p[e]; }
      rsum += __shfl_xor(rsum, 32, 64);
      lrow += rsum;

      // P fragments: pf[s] = S-regs [(s&1)*8 .. +7] of mfma (s>>1), packed bf16
      bf16x8 pf[4];
#pragma unroll
      for (int s4 = 0; s4 < 4; ++s4) {
        union { bf16x8 v; unsigned u[4]; } pu;
        int base = (s4 >> 1) * 16 + (s4 & 1) * 8;
#pragma unroll
        for (int j = 0; j < 4; ++j)
          pu.u[j] = cvtpk_bf16(p[base + 2 * j], p[base + 2 * j + 1]);
        pf[s4] = pu.v;
      }

      __builtin_amdgcn_s_setprio(1);
#pragma unroll
      for (int d0 = 0; d0 < 4; ++d0)
#pragma unroll
        for (int kk = 0; kk < 4; ++kk) {
          int off = ((d0 * 32 + lq) * 128 + kk * 32 + hi * 16) ^ swz;
          o[d0] = __builtin_amdgcn_mfma_f32_32x32x16_bf16(ldT(lV, off), pf[kk], o[d0], 0, 0, 0);
        }
      __builtin_amdgcn_s_setprio(0);
    }

    if (more) {
      WRITE((t + 1) & 1);
      __syncthreads();
    }
  }

  // epilogue: normalize + store. dv = d0*32 + 8*rq + 4*hi + i
  float linv = 1.f / lrow;
  unsigned short* op = aows + ((size_t)(b * SS + qg)) * 2048 + h * 128;
#pragma unroll
  for (int d0 = 0; d0 < 4; ++d0)
#pragma unroll
    for (int rq = 0; rq < 4; ++rq) {
      unsigned w0 = cvtpk_bf16(o[d0][rq * 4 + 0] * linv, o[d0][rq * 4 + 1] * linv);
      unsigned w1 = cvtpk_bf16(o[d0][rq * 4 + 2] * linv, o[d0][rq * 4 + 3] * linv);
      int2 st2; st2.x = (int)w0; st2.y = (int)w1;
      *reinterpret_cast<int2*>(op + d0 * 32 + rq * 8 + hi * 4) = st2;
    }
}

extern "C" void kernel_launch(void* const* d_in, const int* in_sizes, int n_in,
                              void* d_out, int out_size, void* d_ws, size_t ws_size,
                              hipStream_t stream) {
  (void)in_sizes; (void)n_in; (void)out_size; (void)ws_size;
  const float* x  = (const float*)d_in[0];
  const float* fc = (const float*)d_in[1];
  const float* fs = (const float*)d_in[2];
  const float* wq = (const float*)d_in[3];
  const float* wk = (const float*)d_in[4];
  const float* wv = (const float*)d_in[5];
  const float* wo = (const float*)d_in[6];
  float* out = (float*)d_out;
  float* koutF = out + (size_t)BB * SS * HIDD;                  // (B,KV,S,D)
  float* voutF = koutF + (size_t)BB * KVH * SS * DD;            // (B,KV,S,D)

  unsigned short* wcatT = (unsigned short*)d_ws;                // (3072, 2048)
  unsigned short* woT   = wcatT + (size_t)3072 * 2048;          // (2048, 2048)
  unsigned short* xbf   = woT + (size_t)2048 * 2048;            // (4096, 2048)
  unsigned short* qws   = xbf + (size_t)4096 * 2048;            // (B,H,S,D)
  unsigned short* kws   = qws + (size_t)BB * HH * SS * DD;      // (B,KV,S,D)
  unsigned short* vTws  = kws + (size_t)BB * KVH * SS * DD;     // (B,KV,D,S)
  unsigned short* aows  = vTws + (size_t)BB * KVH * DD * SS;    // (B*S, H*D)

  k_convert<<<2048, 256, 0, stream>>>(x, xbf, (int)((size_t)4096 * 2048 / 4));
  dim3 tb(32, 8);
  k_transpose<<<dim3(64, 64), tb, 0, stream>>>(wq, wcatT, 2048, 2048);
  k_transpose<<<dim3(16, 64), tb, 0, stream>>>(wk, wcatT + (size_t)2048 * 2048, 2048, 512);
  k_transpose<<<dim3(16, 64), tb, 0, stream>>>(wv, wcatT + (size_t)2560 * 2048, 2048, 512);
  k_transpose<<<dim3(64, 64), tb, 0, stream>>>(wo, woT, 2048, 2048);

  k_gemm<1><<<dim3(32, 24), 256, 0, stream>>>(xbf, wcatT, nullptr, qws, kws, vTws,
                                              koutF, voutF, fc, fs);
  k_attn<<<512, 256, 0, stream>>>(qws, kws, vTws, aows);
  k_gemm<0><<<dim3(32, 16), 256, 0, stream>>>(aows, woT, out, nullptr, nullptr, nullptr,
                                              nullptr, nullptr, nullptr, nullptr);
}

// Round 4
// 254.584 us; speedup vs baseline: 4.1782x; 1.0938x over previous
//
#include <hip/hip_runtime.h>
#include <stdint.h>

// Problem constants
#define BB 2
#define SS 2048
#define HIDD 2048
#define HH 16
#define KVH 4
#define DD 128
#define KDIM 2048

typedef short bf16x4 __attribute__((ext_vector_type(4)));
typedef short bf16x8 __attribute__((ext_vector_type(8)));
typedef float f32x4 __attribute__((ext_vector_type(4)));
typedef float f32x16 __attribute__((ext_vector_type(16)));

__device__ __forceinline__ unsigned short f2b(float f) {
  union { float f; unsigned u; } v; v.f = f;
  unsigned r = v.u + 0x7FFFu + ((v.u >> 16) & 1u);
  return (unsigned short)(r >> 16);
}

__device__ __forceinline__ unsigned cvtpk_bf16(float a, float b) {
  unsigned r;
  asm("v_cvt_pk_bf16_f32 %0, %1, %2" : "=v"(r) : "v"(a), "v"(b));
  return r;
}

// async global->LDS, 16B per lane; LDS dest is wave-uniform base + lane*16
__device__ __forceinline__ void gload16(const unsigned short* g, unsigned short* l) {
  __builtin_amdgcn_global_load_lds(
      (const __attribute__((address_space(1))) unsigned int*)(g),
      (__attribute__((address_space(3))) unsigned int*)(l), 16, 0, 0);
}

// 16B LDS tile read (pre-swizzled offset computed at call site)
__device__ __forceinline__ bf16x8 ldT(const char* lds, int byteoff) {
  union { bf16x8 v; int4 q; } u;
  u.q = *reinterpret_cast<const int4*>(lds + byteoff);
  return u.v;
}

// K-dim interleave perm within 32-elem blocks: frag(g) = one contiguous 16B.
// perm(k32) = ((k32>>2)&3)*8 + (k32&3) + ((k32>>4)<<2)

__global__ __launch_bounds__(256) void k_convert(const float* __restrict__ in,
                                                 unsigned short* __restrict__ out, int n4) {
  int i = blockIdx.x * 256 + threadIdx.x;
  int stride = gridDim.x * 256;
  for (; i < n4; i += stride) {
    float4 v = reinterpret_cast<const float4*>(in)[i];
    ushort4 o;
    o.x = f2b(v.x); o.y = f2b(v.y); o.z = f2b(v.z); o.w = f2b(v.w);
    // permute 4-elem chunk position within its 32-elem (8-chunk) block
    int ci = i & 511;            // chunk within row (K=2048 -> 512 chunks)
    int t = ci & 7;
    int ci2 = (ci & ~7) | ((t & 3) << 1) | (t >> 2);
    reinterpret_cast<ushort4*>(out)[(i & ~511) | ci2] = o;
  }
}

// in: (K,N) fp32 row-major -> out: (N,K) bf16 row-major with K-dim interleave perm
__global__ __launch_bounds__(256) void k_transpose(const float* __restrict__ in,
                                                   unsigned short* __restrict__ out,
                                                   int K, int N) {
  __shared__ float tile[32][33];
  int n0 = blockIdx.x * 32, k0 = blockIdx.y * 32;
  int tx = threadIdx.x, ty = threadIdx.y;
#pragma unroll
  for (int j = 0; j < 32; j += 8)
    tile[ty + j][tx] = in[(size_t)(k0 + ty + j) * N + n0 + tx];
  __syncthreads();
  int kp = ((tx >> 2) & 3) * 8 + (tx & 3) + ((tx >> 4) << 2);
#pragma unroll
  for (int j = 0; j < 32; j += 8)
    out[(size_t)(n0 + ty + j) * K + k0 + kp] = f2b(tile[tx][ty + j]);
}

// C = A(M x K) * Bt(N x K)^T, bf16 (K-dim pre-interleaved), 128x128 tile, 4 waves.
// m97 structure: global_load_lds(16B) staging, double-buffered BK=32 LDS,
// one barrier per K-step; frag = single ds_read_b128; slot-XOR bank swizzle.
template <int EPI>
__global__ __launch_bounds__(256) void k_gemm(
    const unsigned short* __restrict__ A, const unsigned short* __restrict__ Bt,
    float* __restrict__ outF, unsigned short* __restrict__ qws,
    unsigned short* __restrict__ kws, unsigned short* __restrict__ vTws,
    float* __restrict__ koutF, float* __restrict__ voutF,
    const float* __restrict__ cosT, const float* __restrict__ sinT) {
  __shared__ __align__(16) unsigned short lA[2][128 * 32];
  __shared__ __align__(16) unsigned short lB[2][128 * 32];
  const int rowbase = blockIdx.x * 128;
  const int colbase = blockIdx.y * 128;
  const int t = threadIdx.x;
  const int wid = t >> 6, lane = t & 63;
  const int g = lane >> 4, c = lane & 15;
  const int wrow = (wid >> 1) * 64, wcol = (wid & 1) * 64;

  const int rloc = lane >> 2, sslot = lane & 3;

  f32x4 acc[4][4] = {};

  const int NT = KDIM / 32;

  auto STAGE = [&](int buf, int kt) {
    const int kbase = kt * 32;
#pragma unroll
    for (int j = 0; j < 2; ++j) {
      int r = wid * 32 + j * 16 + rloc;
      int gch = sslot ^ ((r >> 1) & 3);
      gload16(A + (size_t)(rowbase + r) * KDIM + kbase + gch * 8,
              &lA[buf][(wid * 32 + j * 16) * 32]);
      gload16(Bt + (size_t)(colbase + r) * KDIM + kbase + gch * 8,
              &lB[buf][(wid * 32 + j * 16) * 32]);
    }
  };

  STAGE(0, 0);
  __syncthreads();

  for (int kt = 0; kt < NT; ++kt) {
    const int cur = kt & 1;
    if (kt + 1 < NT) STAGE(cur ^ 1, kt + 1);

    const unsigned short* la = lA[cur];
    const unsigned short* lb = lB[cur];
    bf16x8 af[4], bfm[4];
#pragma unroll
    for (int m = 0; m < 4; ++m) {
      int r = wrow + m * 16 + c;
      int slot = g ^ ((r >> 1) & 3);
      af[m] = *reinterpret_cast<const bf16x8*>(la + r * 32 + slot * 8);
    }
#pragma unroll
    for (int n = 0; n < 4; ++n) {
      int r = wcol + n * 16 + c;
      int slot = g ^ ((r >> 1) & 3);
      bfm[n] = *reinterpret_cast<const bf16x8*>(lb + r * 32 + slot * 8);
    }
#pragma unroll
    for (int m = 0; m < 4; ++m)
#pragma unroll
      for (int n = 0; n < 4; ++n)
        acc[m][n] = __builtin_amdgcn_mfma_f32_16x16x32_bf16(af[m], bfm[n], acc[m][n], 0, 0, 0);
    __syncthreads();
  }

  if (EPI == 0) {
#pragma unroll
    for (int m = 0; m < 4; ++m)
#pragma unroll
      for (int n = 0; n < 4; ++n)
#pragma unroll
        for (int i = 0; i < 4; ++i) {
          int R = rowbase + wrow + m * 16 + g * 4 + i;
          int Cc = colbase + wcol + n * 16 + c;
          outF[(size_t)R * 2048 + Cc] = acc[m][n][i];
        }
  } else {
#pragma unroll
    for (int m = 0; m < 4; ++m) {
#pragma unroll
      for (int n = 0; n < 4; ++n) {
#pragma unroll
        for (int i = 0; i < 4; ++i) {
          float val = acc[m][n][i];
          float partner = __shfl_xor(val, 1, 64);
          int R = rowbase + wrow + m * 16 + g * 4 + i;
          int Cc = colbase + wcol + n * 16 + c;
          int b = R >> 11, s = R & 2047;
          int d = Cc & 127;
          int j = d >> 1;
          float cs = cosT[s * 64 + j], sn = sinT[s * 64 + j];
          float ro = ((d & 1) == 0) ? (val * cs - partner * sn)
                                    : (partner * sn + val * cs);
          if (Cc < 2048) {
            int h = Cc >> 7;
            qws[((size_t)(b * HH + h) * SS + s) * DD + d] = f2b(ro);
          } else if (Cc < 2560) {
            int kvh = (Cc - 2048) >> 7;
            size_t idx = ((size_t)(b * KVH + kvh) * SS + s) * DD + d;
            koutF[idx] = ro;
            kws[idx] = f2b(ro);
          } else {
            int kvh = (Cc - 2560) >> 7;
            size_t idx = ((size_t)(b * KVH + kvh) * SS + s) * DD + d;
            voutF[idx] = val;
            vTws[((size_t)(b * KVH + kvh) * DD + d) * SS + s] = f2b(val);
          }
        }
      }
    }
  }
}

// Flash attention, 32x32 MFMA, double-swapped operands (unchanged from R2,
// except aows stores with the K-dim interleave perm for GEMM2 consumption).
__global__ __launch_bounds__(256, 2) void k_attn(const unsigned short* __restrict__ qws,
                                                 const unsigned short* __restrict__ kws,
                                                 const unsigned short* __restrict__ vT,
                                                 unsigned short* __restrict__ aows) {
  __shared__ __align__(16) char lds[2][32768];  // per buf: K 16KB | V 16KB
  const int tid = threadIdx.x;
  const int lane = tid & 63;
  const int w = tid >> 6;
  const int lq = lane & 31;   // this lane's q-column
  const int hi = lane >> 5;   // k-parity half

  const int bid = blockIdx.x;
  const int chunk = (bid < 256) ? (15 - (bid >> 5)) : ((bid - 256) >> 5);
  const int head = bid & 31;
  const int b = head >> 4, h = head & 15;
  const int kv = h >> 2;
  const int q0 = chunk * 128;
  const int q0w = q0 + w * 32;
  const int qg = q0w + lq;
  const int NT = chunk * 2 + 2;
  const float cl2 = 0.12751743f;  // (1/sqrt(128)) * log2(e)

  const unsigned short* qp = qws + ((size_t)(b * HH + h) * SS + qg) * DD;
  bf16x8 qf[8];
#pragma unroll
  for (int ks = 0; ks < 8; ++ks) {
    union { bf16x8 v8; bf16x4 v4[2]; } u;
    const unsigned short* p = qp + ks * 16 + hi * 4;
    u.v4[0] = *reinterpret_cast<const bf16x4*>(p);
    u.v4[1] = *reinterpret_cast<const bf16x4*>(p + 8);
    qf[ks] = u.v8;
  }

  const unsigned short* kbase = kws + (size_t)(b * KVH + kv) * SS * DD;
  const unsigned short* vbase = vT + (size_t)(b * KVH + kv) * DD * SS;

  const int krow = tid >> 2, kslB = tid & 3;   // K: 64 rows x 16 slots(16B)
  const int vrow = tid >> 1, vslB = tid & 1;   // V: 128 rows x 8 slots(16B)
  int2 kreg[8], vreg[8];

  auto ISSUE = [&](int t) {
    const int kb = t * 64;
#pragma unroll
    for (int ss = 0; ss < 4; ++ss) {
      int sl = kslB + ss * 4, ks = sl >> 1, h2 = sl & 1;
      const unsigned short* src = kbase + (size_t)(kb + krow) * DD + ks * 16 + h2 * 4;
      kreg[2 * ss]     = *reinterpret_cast<const int2*>(src);
      kreg[2 * ss + 1] = *reinterpret_cast<const int2*>(src + 8);
    }
#pragma unroll
    for (int ss = 0; ss < 4; ++ss) {
      int sl = vslB + ss * 2, kk = sl >> 1, h2 = sl & 1;
      const unsigned short* src = vbase + (size_t)vrow * SS + kb + kk * 16 + h2 * 4;
      vreg[2 * ss]     = *reinterpret_cast<const int2*>(src);
      vreg[2 * ss + 1] = *reinterpret_cast<const int2*>(src + 8);
    }
  };
  auto WRITE = [&](int buf) {
    char* lK = lds[buf];
    char* lV = lds[buf] + 16384;
#pragma unroll
    for (int ss = 0; ss < 4; ++ss) {
      int sl = kslB + ss * 4, ks = sl >> 1, h2 = sl & 1;
      int off = (krow * 256 + ks * 32 + h2 * 16) ^ ((krow & 15) << 4);
      int4 wv; wv.x = kreg[2*ss].x; wv.y = kreg[2*ss].y; wv.z = kreg[2*ss+1].x; wv.w = kreg[2*ss+1].y;
      *reinterpret_cast<int4*>(lK + off) = wv;
    }
#pragma unroll
    for (int ss = 0; ss < 4; ++ss) {
      int sl = vslB + ss * 2, kk = sl >> 1, h2 = sl & 1;
      int off = (vrow * 128 + kk * 32 + h2 * 16) ^ ((vrow & 15) << 4);
      int4 wv; wv.x = vreg[2*ss].x; wv.y = vreg[2*ss].y; wv.z = vreg[2*ss+1].x; wv.w = vreg[2*ss+1].y;
      *reinterpret_cast<int4*>(lV + off) = wv;
    }
  };

  f32x16 o[4] = {};
  float mrow = -1e30f, lrow = 0.f;

  ISSUE(0);
  WRITE(0);
  __syncthreads();

  for (int t = 0; t < NT; ++t) {
    const bool more = (t + 1 < NT);
    if (more) ISSUE(t + 1);

    if (t * 64 <= q0w + 31) {
      const char* lK = lds[t & 1];
      const char* lV = lds[t & 1] + 16384;
      const int swz = ((lq & 15) << 4);

      f32x16 s[2];
      __builtin_amdgcn_s_setprio(1);
#pragma unroll
      for (int mf = 0; mf < 2; ++mf) {
        f32x16 acc = {};
#pragma unroll
        for (int ks = 0; ks < 8; ++ks) {
          int off = ((mf * 32 + lq) * 256 + ks * 32 + hi * 16) ^ swz;
          acc = __builtin_amdgcn_mfma_f32_32x32x16_bf16(ldT(lK, off), qf[ks], acc, 0, 0, 0);
        }
        s[mf] = acc;
      }
      __builtin_amdgcn_s_setprio(0);

      const bool needMask = (t * 64 + 63) > q0w;
      const int kq = t * 64 + 4 * hi - qg;
      float p[32];
      float rowmax = -1e30f;
#pragma unroll
      for (int mf = 0; mf < 2; ++mf)
#pragma unroll
        for (int r = 0; r < 16; ++r) {
          float v = s[mf][r] * cl2;
          if (needMask) {
            int kl = mf * 32 + (r & 3) + 8 * (r >> 2);
            if (kq + kl > 0) v = -1e30f;
          }
          p[mf * 16 + r] = v;
          rowmax = fmaxf(rowmax, v);
        }
      rowmax = fmaxf(rowmax, __shfl_xor(rowmax, 32, 64));

      if (__any(rowmax > mrow + 8.f)) {  // T13 defer-max
        float mnew = fmaxf(mrow, rowmax);
        float fac = exp2f(mrow - mnew);
        mrow = mnew;
        lrow *= fac;
#pragma unroll
        for (int d0 = 0; d0 < 4; ++d0)
#pragma unroll
          for (int r = 0; r < 16; ++r) o[d0][r] *= fac;
      }

      float rsum = 0.f;
#pragma unroll
      for (int e = 0; e < 32; ++e) { p[e] = exp2f(p[e] - mrow); rsum += p[e]; }
      rsum += __shfl_xor(rsum, 32, 64);
      lrow += rsum;

      bf16x8 pf[4];
#pragma unroll
      for (int s4 = 0; s4 < 4; ++s4) {
        union { bf16x8 v; unsigned u[4]; } pu;
        int base = (s4 >> 1) * 16 + (s4 & 1) * 8;
#pragma unroll
        for (int j = 0; j < 4; ++j)
          pu.u[j] = cvtpk_bf16(p[base + 2 * j], p[base + 2 * j + 1]);
        pf[s4] = pu.v;
      }

      __builtin_amdgcn_s_setprio(1);
#pragma unroll
      for (int d0 = 0; d0 < 4; ++d0)
#pragma unroll
        for (int kk = 0; kk < 4; ++kk) {
          int off = ((d0 * 32 + lq) * 128 + kk * 32 + hi * 16) ^ swz;
          o[d0] = __builtin_amdgcn_mfma_f32_32x32x16_bf16(ldT(lV, off), pf[kk], o[d0], 0, 0, 0);
        }
      __builtin_amdgcn_s_setprio(0);
    }

    if (more) {
      WRITE((t + 1) & 1);
      __syncthreads();
    }
  }

  // epilogue: normalize + store with K-dim interleave perm for GEMM2.
  // d32 = 8*rq + 4*hi + i  ->  pos = 8*((2rq+hi)&3) + 4*(rq>>1) + i
  float linv = 1.f / lrow;
  unsigned short* op = aows + ((size_t)(b * SS + qg)) * 2048 + h * 128;
#pragma unroll
  for (int d0 = 0; d0 < 4; ++d0)
#pragma unroll
    for (int rq = 0; rq < 4; ++rq) {
      unsigned w0 = cvtpk_bf16(o[d0][rq * 4 + 0] * linv, o[d0][rq * 4 + 1] * linv);
      unsigned w1 = cvtpk_bf16(o[d0][rq * 4 + 2] * linv, o[d0][rq * 4 + 3] * linv);
      int2 st2; st2.x = (int)w0; st2.y = (int)w1;
      int pos = 8 * ((2 * rq + hi) & 3) + 4 * (rq >> 1);
      *reinterpret_cast<int2*>(op + d0 * 32 + pos) = st2;
    }
}

extern "C" void kernel_launch(void* const* d_in, const int* in_sizes, int n_in,
                              void* d_out, int out_size, void* d_ws, size_t ws_size,
                              hipStream_t stream) {
  (void)in_sizes; (void)n_in; (void)out_size; (void)ws_size;
  const float* x  = (const float*)d_in[0];
  const float* fc = (const float*)d_in[1];
  const float* fs = (const float*)d_in[2];
  const float* wq = (const float*)d_in[3];
  const float* wk = (const float*)d_in[4];
  const float* wv = (const float*)d_in[5];
  const float* wo = (const float*)d_in[6];
  float* out = (float*)d_out;
  float* koutF = out + (size_t)BB * SS * HIDD;                  // (B,KV,S,D)
  float* voutF = koutF + (size_t)BB * KVH * SS * DD;            // (B,KV,S,D)

  unsigned short* wcatT = (unsigned short*)d_ws;                // (3072, 2048)
  unsigned short* woT   = wcatT + (size_t)3072 * 2048;          // (2048, 2048)
  unsigned short* xbf   = woT + (size_t)2048 * 2048;            // (4096, 2048)
  unsigned short* qws   = xbf + (size_t)4096 * 2048;            // (B,H,S,D)
  unsigned short* kws   = qws + (size_t)BB * HH * SS * DD;      // (B,KV,S,D)
  unsigned short* vTws  = kws + (size_t)BB * KVH * SS * DD;     // (B,KV,D,S)
  unsigned short* aows  = vTws + (size_t)BB * KVH * DD * SS;    // (B*S, H*D)

  k_convert<<<2048, 256, 0, stream>>>(x, xbf, (int)((size_t)4096 * 2048 / 4));
  dim3 tb(32, 8);
  k_transpose<<<dim3(64, 64), tb, 0, stream>>>(wq, wcatT, 2048, 2048);
  k_transpose<<<dim3(16, 64), tb, 0, stream>>>(wk, wcatT + (size_t)2048 * 2048, 2048, 512);
  k_transpose<<<dim3(16, 64), tb, 0, stream>>>(wv, wcatT + (size_t)2560 * 2048, 2048, 512);
  k_transpose<<<dim3(64, 64), tb, 0, stream>>>(wo, woT, 2048, 2048);

  k_gemm<1><<<dim3(32, 24), 256, 0, stream>>>(xbf, wcatT, nullptr, qws, kws, vTws,
                                              koutF, voutF, fc, fs);
  k_attn<<<512, 256, 0, stream>>>(qws, kws, vTws, aows);
  k_gemm<0><<<dim3(32, 16), 256, 0, stream>>>(aows, woT, out, nullptr, nullptr, nullptr,
                                              nullptr, nullptr, nullptr, nullptr);
}